// Round 5
// baseline (413.148 us; speedup 1.0000x reference)
//
#include <hip/hip_runtime.h>
#include <hip/hip_bf16.h>
#include <math.h>

// Fused QKV(+bias) -> RoPE -> 4-head causal attention -> FC2(+bias) -> SiLU
// B=2048, L=119, D=128, H=4, HD=32. fp32 in/out, bf16 MFMA internally.
// Head split: model channel c = d*4 + h. Head merge: out channel c' = h*32 + d.
//
// Round 4: keep round-3's 2-blocks/CU LDS layout; eliminate the scratch
// spills that made round 3 memory-bound (VGPR_Count=64 + 1.09 GB hbm_bytes).
//  - amdgpu_waves_per_eu(4,4): pin allocator to the 128-VGPR / 4-wave tier.
//  - QKV computed in 3 channel-pairs with immediate epilogue: acc[2][2] (16
//    regs) instead of acc[2][6] (48); af reloaded per head-group so it is not
//    live across attention.  Peak live ~56 regs.
// LDS: qs/ks [2][119][34], vT/Ps stride 128 + XOR ^((row&7)<<3) = 81,520 B.
// MFMA 16x16x32_bf16: A/B lane&15=row, k=(lane>>4)*8+j; C/D col=lane&15,
// row=(lane>>4)*4+reg [m89].

#define L_SEQ 119
#define D_MODEL 128
#define SCALE 0.17677669529663687f  // 1/sqrt(32)
#define NEGINF -1e30f

typedef __bf16 bf16x8 __attribute__((ext_vector_type(8)));
typedef float f32x4 __attribute__((ext_vector_type(4)));

__global__ void rope_tab_kernel(float2* __restrict__ tab) {
  int i = blockIdx.x * blockDim.x + threadIdx.x;
  if (i >= L_SEQ * 64) return;
  int l = i >> 6, j = i & 63;
  float inv = 1.0f / powf(10000.0f, (float)(2 * j) / 128.0f);
  float f = (float)l * inv;
  float c = cosf(f), s = sinf(f);
  tab[i] = make_float2(__bfloat162float(__float2bfloat16(c)),
                       __bfloat162float(__float2bfloat16(s)));
}

// Wb fragment layout: flat = ((nt*4 + kb)*64 + lane)*8 + j
//   reordered channel n~ = nt*16 + (lane&15); k = kb*32 + (lane>>4)*8 + j
//   n~ = h*96 + qkv*32 + d  ->  source row = qkv*128 + d*4 + h
__global__ void wprep_kernel(const float* __restrict__ Wqkv,
                             const float* __restrict__ bqkv,
                             __bf16* __restrict__ Wb, float* __restrict__ bb) {
  int i = blockIdx.x * 256 + threadIdx.x;  // 0..49151
  int j = i & 7, lane = (i >> 3) & 63, kb = (i >> 9) & 3, nt = i >> 11;
  int ln15 = lane & 15, kg = lane >> 4;
  int nch = nt * 16 + ln15;
  int h = nch / 96, rem = nch % 96, qkv = rem >> 5, d = rem & 31;
  int srow = qkv * 128 + d * 4 + h;
  int k = kb * 32 + kg * 8 + j;
  Wb[i] = (__bf16)Wqkv[srow * 128 + k];
  if (i < 384) {
    int h2 = i / 96, r2 = i % 96, q2 = r2 >> 5, d2 = r2 & 31;
    bb[i] = bqkv[q2 * 128 + d2 * 4 + h2];
  }
}

__global__ __launch_bounds__(512)
__attribute__((amdgpu_waves_per_eu(4, 4))) void fused_qkv_attn(
    const float* __restrict__ x, const __bf16* __restrict__ Wb,
    const float* __restrict__ bb, const float2* __restrict__ tab,
    float* __restrict__ out) {
  __shared__ __align__(16) __bf16 qs[2 * 119 * 34];   // 16,184 B
  __shared__ __align__(16) __bf16 ks[2 * 119 * 34];   // 16,184 B
  __shared__ __align__(16) __bf16 vT[2 * 32 * 128];   // 16,384 B (XOR-swizzled)
  __shared__ __align__(16) __bf16 Ps[8 * 16 * 128];   // 32,768 B (XOR-swizzled)

  const int t = threadIdx.x, b = blockIdx.x;
  const int lane = t & 63, wv = t >> 6;
  const int ln15 = lane & 15, kg = lane >> 4;
  const int msel = wv & 3, hh = wv >> 2;  // wave: M-tiles {msel, msel+4}, local head hh

  // ---- zero vT tail cols 119..127 (PV's P is 0 there; garbage could be NaN)
  for (int i = t; i < 2 * 32 * 9; i += 512) {
    int hl = i / 288, rem = i % 288, rr = rem / 9, cc = L_SEQ + rem % 9;
    int vr = hl * 32 + rr;
    vT[vr * 128 + (cc ^ ((vr & 7) << 3))] = (__bf16)0.0f;
  }

  for (int g = 0; g < 2; ++g) {
    if (g) __syncthreads();  // prior group's attention must finish reading LDS
    const int h = 2 * g + hh;

    // ---- x A-fragments (reloaded per group; L2-hot for g=1)
    bf16x8 af[2][4];
#pragma unroll
    for (int ms = 0; ms < 2; ++ms) {
      int xr = (msel + ms * 4) * 16 + ln15;
      if (xr > L_SEQ - 1) xr = L_SEQ - 1;
      const float* xrow = x + ((size_t)b * L_SEQ + xr) * 128;
#pragma unroll
      for (int kb = 0; kb < 4; ++kb) {
        float4 lo = *(const float4*)&xrow[kb * 32 + kg * 8];
        float4 hi = *(const float4*)&xrow[kb * 32 + kg * 8 + 4];
        bf16x8 v;
        v[0] = (__bf16)lo.x; v[1] = (__bf16)lo.y; v[2] = (__bf16)lo.z; v[3] = (__bf16)lo.w;
        v[4] = (__bf16)hi.x; v[5] = (__bf16)hi.y; v[6] = (__bf16)hi.z; v[7] = (__bf16)hi.w;
        af[ms][kb] = v;
      }
    }

    // ---- QKV in 3 channel-pairs, epilogue immediately after each pair
#pragma unroll
    for (int pair = 0; pair < 3; ++pair) {
      f32x4 acc[2][2] = {};  // [ms][half]
#pragma unroll
      for (int half = 0; half < 2; ++half) {
        const int nt = g * 12 + hh * 6 + pair * 2 + half;
        bf16x8 wf[4];
#pragma unroll
        for (int kb = 0; kb < 4; ++kb)
          wf[kb] = *(const bf16x8*)&Wb[(((nt * 4 + kb) * 64) + lane) * 8];
#pragma unroll
        for (int kb = 0; kb < 4; ++kb) {
          acc[0][half] = __builtin_amdgcn_mfma_f32_16x16x32_bf16(af[0][kb], wf[kb], acc[0][half], 0, 0, 0);
          acc[1][half] = __builtin_amdgcn_mfma_f32_16x16x32_bf16(af[1][kb], wf[kb], acc[1][half], 0, 0, 0);
        }
      }
      const float b0 = bb[(g * 12 + hh * 6 + pair * 2) * 16 + ln15];
      const float b1 = bb[(g * 12 + hh * 6 + pair * 2 + 1) * 16 + ln15];
#pragma unroll
      for (int ms = 0; ms < 2; ++ms) {
        const int mt = msel + ms * 4;
#pragma unroll
        for (int r = 0; r < 4; ++r) {
          int l = mt * 16 + kg * 4 + r;
          if (l < L_SEQ) {
            float v1 = acc[ms][0][r] + b0, v2 = acc[ms][1][r] + b1;
            if (pair < 2) {
              float2 cs = tab[l * 64 + 4 * ln15 + h];
              __bf16* base = pair ? ks : qs;
              base[(hh * L_SEQ + l) * 34 + ln15]      = (__bf16)(v1 * cs.x + v2 * cs.y);
              base[(hh * L_SEQ + l) * 34 + 16 + ln15] = (__bf16)(v2 * cs.x - v1 * cs.y);
            } else {
              int vr0 = hh * 32 + ln15, vr1 = vr0 + 16;
              vT[vr0 * 128 + (l ^ ((vr0 & 7) << 3))] = (__bf16)v1;
              vT[vr1 * 128 + (l ^ ((vr1 & 7) << 3))] = (__bf16)v2;
            }
          }
        }
      }
    }
    __syncthreads();

    // ---- attention: wave -> (head hh, m2 in {msel, msel+4}), no more barriers
    __bf16* Pw = &Ps[wv * 16 * 128];
#pragma unroll
    for (int ms = 0; ms < 2; ++ms) {
      const int m2 = msel + ms * 4;
      int qrow = m2 * 16 + ln15;
      if (qrow > L_SEQ - 1) qrow = L_SEQ - 1;
      bf16x8 qf = *(const bf16x8*)&qs[(hh * L_SEQ + qrow) * 34 + kg * 8];
      f32x4 s[8];
#pragma unroll
      for (int nt = 0; nt < 8; ++nt) {
        int krow = nt * 16 + ln15;
        if (krow > L_SEQ - 1) krow = L_SEQ - 1;
        f32x4 z = {};
        s[nt] = __builtin_amdgcn_mfma_f32_16x16x32_bf16(
            qf, *(const bf16x8*)&ks[(hh * L_SEQ + krow) * 34 + kg * 8], z, 0, 0, 0);
      }
#pragma unroll
      for (int r = 0; r < 4; ++r) {
        int l = m2 * 16 + kg * 4 + r;
        float v[8], mx = NEGINF;
#pragma unroll
        for (int nt = 0; nt < 8; ++nt) {
          int m = nt * 16 + ln15;
          v[nt] = (m <= l) ? s[nt][r] * SCALE : NEGINF;
          mx = fmaxf(mx, v[nt]);
        }
#pragma unroll
        for (int off = 1; off < 16; off <<= 1) mx = fmaxf(mx, __shfl_xor(mx, off));
        float sum = 0.f;
#pragma unroll
        for (int nt = 0; nt < 8; ++nt) { v[nt] = __expf(v[nt] - mx); sum += v[nt]; }
#pragma unroll
        for (int off = 1; off < 16; off <<= 1) sum += __shfl_xor(sum, off);
        float inv = 1.0f / sum;
        int pr = kg * 4 + r;
#pragma unroll
        for (int nt = 0; nt < 8; ++nt)
          Pw[pr * 128 + ((nt * 16 + ln15) ^ ((pr & 7) << 3))] = (__bf16)(v[nt] * inv);
      }
      f32x4 o[2] = {};
#pragma unroll
      for (int n2 = 0; n2 < 2; ++n2)
#pragma unroll
        for (int kb = 0; kb < 4; ++kb) {
          int vr = hh * 32 + n2 * 16 + ln15;
          o[n2] = __builtin_amdgcn_mfma_f32_16x16x32_bf16(
              *(const bf16x8*)&Pw[ln15 * 128 + ((kb * 32 + kg * 8) ^ ((ln15 & 7) << 3))],
              *(const bf16x8*)&vT[vr * 128 + ((kb * 32 + kg * 8) ^ ((vr & 7) << 3))],
              o[n2], 0, 0, 0);
        }
#pragma unroll
      for (int n2 = 0; n2 < 2; ++n2)
#pragma unroll
        for (int r = 0; r < 4; ++r) {
          int l = m2 * 16 + kg * 4 + r;
          if (l < L_SEQ)
            out[((size_t)b * L_SEQ + l) * 128 + h * 32 + n2 * 16 + ln15] = o[n2][r];
        }
    }
  }
}

// FC2 + bias + SiLU via MFMA, in-place on d_out. Block owns 128 rows.
__global__ __launch_bounds__(256) void fc2_silu_kernel(
    const float* __restrict__ Wfc2, const float* __restrict__ bfc2,
    float* __restrict__ io) {
  __shared__ __align__(16) __bf16 yl[128 * 136];
  __shared__ __align__(16) __bf16 wl[128 * 136];
  __shared__ float blc[128];
  const int t = threadIdx.x;
  const size_t r0 = (size_t)blockIdx.x * 128;
  for (int i = t; i < 128 * 32; i += 256) {
    int row = i >> 5, c4 = i & 31;
    float4 a = *(const float4*)&io[(r0 + row) * 128 + c4 * 4];
    float4 w = *(const float4*)&Wfc2[row * 128 + c4 * 4];
    __bf16* yd = &yl[row * 136 + c4 * 4];
    yd[0] = (__bf16)a.x; yd[1] = (__bf16)a.y; yd[2] = (__bf16)a.z; yd[3] = (__bf16)a.w;
    __bf16* wd = &wl[row * 136 + c4 * 4];
    wd[0] = (__bf16)w.x; wd[1] = (__bf16)w.y; wd[2] = (__bf16)w.z; wd[3] = (__bf16)w.w;
  }
  if (t < 128) blc[t] = bfc2[t];
  __syncthreads();
  const int lane = t & 63, wv = t >> 6;
  const int ln15 = lane & 15, kg = lane >> 4;
#pragma unroll
  for (int mm = 0; mm < 2; ++mm) {
    int mtl = wv * 2 + mm;
    bf16x8 af[4];
#pragma unroll
    for (int kb = 0; kb < 4; ++kb)
      af[kb] = *(const bf16x8*)&yl[(mtl * 16 + ln15) * 136 + kb * 32 + kg * 8];
#pragma unroll
    for (int nt = 0; nt < 8; ++nt) {
      f32x4 acc = {};
#pragma unroll
      for (int kb = 0; kb < 4; ++kb)
        acc = __builtin_amdgcn_mfma_f32_16x16x32_bf16(
            af[kb], *(const bf16x8*)&wl[(nt * 16 + ln15) * 136 + kb * 32 + kg * 8],
            acc, 0, 0, 0);
#pragma unroll
      for (int r = 0; r < 4; ++r) {
        int row = mtl * 16 + kg * 4 + r, c = nt * 16 + ln15;
        float vv = acc[r] + blc[c];
        io[(r0 + row) * 128 + c] = vv / (1.0f + __expf(-vv));
      }
    }
  }
}

extern "C" void kernel_launch(void* const* d_in, const int* in_sizes, int n_in,
                              void* d_out, int out_size, void* d_ws,
                              size_t ws_size, hipStream_t stream) {
  const float* x = (const float*)d_in[0];
  const float* Wqkv = (const float*)d_in[1];
  const float* bqkv = (const float*)d_in[2];
  const float* Wfc2 = (const float*)d_in[3];
  const float* bfc2 = (const float*)d_in[4];
  float* out = (float*)d_out;

  char* ws = (char*)d_ws;
  float2* tab = (float2*)ws;                    // 60,928 B
  __bf16* Wb = (__bf16*)(ws + 61440);           // 98,304 B
  float* bb = (float*)(ws + 61440 + 98304);     // 1,536 B  (total 161,280 B)

  const int B = in_sizes[0] / (L_SEQ * D_MODEL);  // 2048
  rope_tab_kernel<<<(L_SEQ * 64 + 255) / 256, 256, 0, stream>>>(tab);
  wprep_kernel<<<192, 256, 0, stream>>>(Wqkv, bqkv, Wb, bb);
  fused_qkv_attn<<<B, 512, 0, stream>>>(x, Wb, bb, tab, out);
  fc2_silu_kernel<<<(B * L_SEQ) / 128, 256, 0, stream>>>(Wfc2, bfc2, out);
}

// Round 6
// 237.986 us; speedup vs baseline: 1.7360x; 1.7360x over previous
//
#include <hip/hip_runtime.h>
#include <hip/hip_bf16.h>
#include <math.h>

// Fused QKV(+bias) -> RoPE -> 4-head causal attention -> FC2(+bias) -> SiLU
// B=2048, L=119, D=128, H=4, HD=32. fp32 in/out, bf16 MFMA internally.
// Head split: model channel c = d*4 + h. Head merge: out channel c' = h*32 + d.
//
// Round 5: round-3 LDS layout (81,520 B -> exactly 2 blocks/CU) with NO
// occupancy hints. Evidence: plain __launch_bounds__(512) -> VGPR 108, zero
// spill (R2); any min-waves hint -> allocator picks 64 VGPR + ~430 MB scratch
// traffic each way (R3/R4, memory-bound). Register diet so <=128 is easy:
// QKV in 3 channel-pairs (acc[2][2]), wf[4] per half, af[2][4] loaded ONCE.
// LDS: qs/ks [2][119][34] (17-word rows, conflict-free), vT/Ps stride 128
// XOR-swizzled ^((row&7)<<3) both sides (rule #21).
// MFMA 16x16x32_bf16: A/B lane&15=row, k=(lane>>4)*8+j; C/D col=lane&15,
// row=(lane>>4)*4+reg [m89].

#define L_SEQ 119
#define D_MODEL 128
#define SCALE 0.17677669529663687f  // 1/sqrt(32)
#define NEGINF -1e30f

typedef __bf16 bf16x8 __attribute__((ext_vector_type(8)));
typedef float f32x4 __attribute__((ext_vector_type(4)));

__global__ void rope_tab_kernel(float2* __restrict__ tab) {
  int i = blockIdx.x * blockDim.x + threadIdx.x;
  if (i >= L_SEQ * 64) return;
  int l = i >> 6, j = i & 63;
  float inv = 1.0f / powf(10000.0f, (float)(2 * j) / 128.0f);
  float f = (float)l * inv;
  float c = cosf(f), s = sinf(f);
  tab[i] = make_float2(__bfloat162float(__float2bfloat16(c)),
                       __bfloat162float(__float2bfloat16(s)));
}

// Wb fragment layout: flat = ((nt*4 + kb)*64 + lane)*8 + j
//   reordered channel n~ = nt*16 + (lane&15); k = kb*32 + (lane>>4)*8 + j
//   n~ = h*96 + qkv*32 + d  ->  source row = qkv*128 + d*4 + h
__global__ void wprep_kernel(const float* __restrict__ Wqkv,
                             const float* __restrict__ bqkv,
                             __bf16* __restrict__ Wb, float* __restrict__ bb) {
  int i = blockIdx.x * 256 + threadIdx.x;  // 0..49151
  int j = i & 7, lane = (i >> 3) & 63, kb = (i >> 9) & 3, nt = i >> 11;
  int ln15 = lane & 15;
  int nch = nt * 16 + ln15;
  int h = nch / 96, rem = nch % 96, qkv = rem >> 5, d = rem & 31;
  int srow = qkv * 128 + d * 4 + h;
  int k = kb * 32 + (lane >> 4) * 8 + j;
  Wb[i] = (__bf16)Wqkv[srow * 128 + k];
  if (i < 384) {
    int h2 = i / 96, r2 = i % 96, q2 = r2 >> 5, d2 = r2 & 31;
    bb[i] = bqkv[q2 * 128 + d2 * 4 + h2];
  }
}

__global__ __launch_bounds__(512) void fused_qkv_attn(
    const float* __restrict__ x, const __bf16* __restrict__ Wb,
    const float* __restrict__ bb, const float2* __restrict__ tab,
    float* __restrict__ out) {
  __shared__ __align__(16) __bf16 qs[2 * 119 * 34];   // 16,184 B
  __shared__ __align__(16) __bf16 ks[2 * 119 * 34];   // 16,184 B
  __shared__ __align__(16) __bf16 vT[2 * 32 * 128];   // 16,384 B (XOR-swizzled)
  __shared__ __align__(16) __bf16 Ps[8 * 16 * 128];   // 32,768 B (XOR-swizzled)

  const int t = threadIdx.x, b = blockIdx.x;
  const int lane = t & 63, wv = t >> 6;
  const int ln15 = lane & 15, kg = lane >> 4;
  const int msel = wv & 3, hh = wv >> 2;  // wave: M-tiles {msel, msel+4}, local head hh

  // ---- zero vT tail cols 119..127 (PV's P is 0 there; garbage could be NaN)
  for (int i = t; i < 2 * 32 * 9; i += 512) {
    int hl = i / 288, rem = i % 288, rr = rem / 9, cc = L_SEQ + rem % 9;
    int vr = hl * 32 + rr;
    vT[vr * 128 + (cc ^ ((vr & 7) << 3))] = (__bf16)0.0f;
  }

  // ---- x A-fragments, loaded ONCE per block (live across both groups)
  bf16x8 af[2][4];
#pragma unroll
  for (int ms = 0; ms < 2; ++ms) {
    int xr = (msel + ms * 4) * 16 + ln15;
    if (xr > L_SEQ - 1) xr = L_SEQ - 1;
    const float* xrow = x + ((size_t)b * L_SEQ + xr) * 128;
#pragma unroll
    for (int kb = 0; kb < 4; ++kb) {
      float4 lo = *(const float4*)&xrow[kb * 32 + kg * 8];
      float4 hi = *(const float4*)&xrow[kb * 32 + kg * 8 + 4];
      bf16x8 v;
      v[0] = (__bf16)lo.x; v[1] = (__bf16)lo.y; v[2] = (__bf16)lo.z; v[3] = (__bf16)lo.w;
      v[4] = (__bf16)hi.x; v[5] = (__bf16)hi.y; v[6] = (__bf16)hi.z; v[7] = (__bf16)hi.w;
      af[ms][kb] = v;
    }
  }

  for (int g = 0; g < 2; ++g) {
    if (g) __syncthreads();  // prior group's attention must finish reading LDS
    const int h = 2 * g + hh;

    // ---- QKV in 3 channel-pairs, epilogue immediately after each pair
#pragma unroll
    for (int pair = 0; pair < 3; ++pair) {
      f32x4 acc[2][2] = {};  // [ms][half]
#pragma unroll
      for (int half = 0; half < 2; ++half) {
        const int nt = g * 12 + hh * 6 + pair * 2 + half;
        bf16x8 wf[4];
#pragma unroll
        for (int kb = 0; kb < 4; ++kb)
          wf[kb] = *(const bf16x8*)&Wb[(((nt * 4 + kb) * 64) + lane) * 8];
#pragma unroll
        for (int kb = 0; kb < 4; ++kb) {
          acc[0][half] = __builtin_amdgcn_mfma_f32_16x16x32_bf16(af[0][kb], wf[kb], acc[0][half], 0, 0, 0);
          acc[1][half] = __builtin_amdgcn_mfma_f32_16x16x32_bf16(af[1][kb], wf[kb], acc[1][half], 0, 0, 0);
        }
      }
      const float b0 = bb[(g * 12 + hh * 6 + pair * 2) * 16 + ln15];
      const float b1 = bb[(g * 12 + hh * 6 + pair * 2 + 1) * 16 + ln15];
#pragma unroll
      for (int ms = 0; ms < 2; ++ms) {
        const int mt = msel + ms * 4;
#pragma unroll
        for (int r = 0; r < 4; ++r) {
          int l = mt * 16 + kg * 4 + r;
          if (l < L_SEQ) {
            float v1 = acc[ms][0][r] + b0, v2 = acc[ms][1][r] + b1;
            if (pair < 2) {
              float2 cs = tab[l * 64 + 4 * ln15 + h];
              __bf16* base = pair ? ks : qs;
              base[(hh * L_SEQ + l) * 34 + ln15]      = (__bf16)(v1 * cs.x + v2 * cs.y);
              base[(hh * L_SEQ + l) * 34 + 16 + ln15] = (__bf16)(v2 * cs.x - v1 * cs.y);
            } else {
              int vr0 = hh * 32 + ln15, vr1 = vr0 + 16;
              vT[vr0 * 128 + (l ^ ((vr0 & 7) << 3))] = (__bf16)v1;
              vT[vr1 * 128 + (l ^ ((vr1 & 7) << 3))] = (__bf16)v2;
            }
          }
        }
      }
    }
    __syncthreads();

    // ---- attention: wave -> (head hh, m2 in {msel, msel+4}), no more barriers
    __bf16* Pw = &Ps[wv * 16 * 128];
#pragma unroll
    for (int ms = 0; ms < 2; ++ms) {
      const int m2 = msel + ms * 4;
      int qrow = m2 * 16 + ln15;
      if (qrow > L_SEQ - 1) qrow = L_SEQ - 1;
      bf16x8 qf = *(const bf16x8*)&qs[(hh * L_SEQ + qrow) * 34 + kg * 8];
      f32x4 s[8];
#pragma unroll
      for (int nt = 0; nt < 8; ++nt) {
        int krow = nt * 16 + ln15;
        if (krow > L_SEQ - 1) krow = L_SEQ - 1;
        f32x4 z = {};
        s[nt] = __builtin_amdgcn_mfma_f32_16x16x32_bf16(
            qf, *(const bf16x8*)&ks[(hh * L_SEQ + krow) * 34 + kg * 8], z, 0, 0, 0);
      }
#pragma unroll
      for (int r = 0; r < 4; ++r) {
        int l = m2 * 16 + kg * 4 + r;
        float v[8], mx = NEGINF;
#pragma unroll
        for (int nt = 0; nt < 8; ++nt) {
          int m = nt * 16 + ln15;
          v[nt] = (m <= l) ? s[nt][r] * SCALE : NEGINF;
          mx = fmaxf(mx, v[nt]);
        }
#pragma unroll
        for (int off = 1; off < 16; off <<= 1) mx = fmaxf(mx, __shfl_xor(mx, off));
        float sum = 0.f;
#pragma unroll
        for (int nt = 0; nt < 8; ++nt) { v[nt] = __expf(v[nt] - mx); sum += v[nt]; }
#pragma unroll
        for (int off = 1; off < 16; off <<= 1) sum += __shfl_xor(sum, off);
        float inv = 1.0f / sum;
        int pr = kg * 4 + r;
#pragma unroll
        for (int nt = 0; nt < 8; ++nt)
          Pw[pr * 128 + ((nt * 16 + ln15) ^ ((pr & 7) << 3))] = (__bf16)(v[nt] * inv);
      }
      f32x4 o[2] = {};
#pragma unroll
      for (int n2 = 0; n2 < 2; ++n2)
#pragma unroll
        for (int kb = 0; kb < 4; ++kb) {
          int vr = hh * 32 + n2 * 16 + ln15;
          o[n2] = __builtin_amdgcn_mfma_f32_16x16x32_bf16(
              *(const bf16x8*)&Pw[ln15 * 128 + ((kb * 32 + kg * 8) ^ ((ln15 & 7) << 3))],
              *(const bf16x8*)&vT[vr * 128 + ((kb * 32 + kg * 8) ^ ((vr & 7) << 3))],
              o[n2], 0, 0, 0);
        }
#pragma unroll
      for (int n2 = 0; n2 < 2; ++n2)
#pragma unroll
        for (int r = 0; r < 4; ++r) {
          int l = m2 * 16 + kg * 4 + r;
          if (l < L_SEQ)
            out[((size_t)b * L_SEQ + l) * 128 + h * 32 + n2 * 16 + ln15] = o[n2][r];
        }
    }
  }
}

// FC2 + bias + SiLU via MFMA, in-place on d_out. Block owns 128 rows.
__global__ __launch_bounds__(256) void fc2_silu_kernel(
    const float* __restrict__ Wfc2, const float* __restrict__ bfc2,
    float* __restrict__ io) {
  __shared__ __align__(16) __bf16 yl[128 * 136];
  __shared__ __align__(16) __bf16 wl[128 * 136];
  __shared__ float blc[128];
  const int t = threadIdx.x;
  const size_t r0 = (size_t)blockIdx.x * 128;
  for (int i = t; i < 128 * 32; i += 256) {
    int row = i >> 5, c4 = i & 31;
    float4 a = *(const float4*)&io[(r0 + row) * 128 + c4 * 4];
    float4 w = *(const float4*)&Wfc2[row * 128 + c4 * 4];
    __bf16* yd = &yl[row * 136 + c4 * 4];
    yd[0] = (__bf16)a.x; yd[1] = (__bf16)a.y; yd[2] = (__bf16)a.z; yd[3] = (__bf16)a.w;
    __bf16* wd = &wl[row * 136 + c4 * 4];
    wd[0] = (__bf16)w.x; wd[1] = (__bf16)w.y; wd[2] = (__bf16)w.z; wd[3] = (__bf16)w.w;
  }
  if (t < 128) blc[t] = bfc2[t];
  __syncthreads();
  const int lane = t & 63, wv = t >> 6;
  const int ln15 = lane & 15, kg = lane >> 4;
#pragma unroll
  for (int mm = 0; mm < 2; ++mm) {
    int mtl = wv * 2 + mm;
    bf16x8 af[4];
#pragma unroll
    for (int kb = 0; kb < 4; ++kb)
      af[kb] = *(const bf16x8*)&yl[(mtl * 16 + ln15) * 136 + kb * 32 + kg * 8];
#pragma unroll
    for (int nt = 0; nt < 8; ++nt) {
      f32x4 acc = {};
#pragma unroll
      for (int kb = 0; kb < 4; ++kb)
        acc = __builtin_amdgcn_mfma_f32_16x16x32_bf16(
            af[kb], *(const bf16x8*)&wl[(nt * 16 + ln15) * 136 + kb * 32 + kg * 8],
            acc, 0, 0, 0);
#pragma unroll
      for (int r = 0; r < 4; ++r) {
        int row = mtl * 16 + kg * 4 + r, c = nt * 16 + ln15;
        float vv = acc[r] + blc[c];
        io[(r0 + row) * 128 + c] = vv / (1.0f + __expf(-vv));
      }
    }
  }
}

extern "C" void kernel_launch(void* const* d_in, const int* in_sizes, int n_in,
                              void* d_out, int out_size, void* d_ws,
                              size_t ws_size, hipStream_t stream) {
  const float* x = (const float*)d_in[0];
  const float* Wqkv = (const float*)d_in[1];
  const float* bqkv = (const float*)d_in[2];
  const float* Wfc2 = (const float*)d_in[3];
  const float* bfc2 = (const float*)d_in[4];
  float* out = (float*)d_out;

  char* ws = (char*)d_ws;
  float2* tab = (float2*)ws;                    // 60,928 B
  __bf16* Wb = (__bf16*)(ws + 61440);           // 98,304 B
  float* bb = (float*)(ws + 61440 + 98304);     // 1,536 B  (total 161,280 B)

  const int B = in_sizes[0] / (L_SEQ * D_MODEL);  // 2048
  rope_tab_kernel<<<(L_SEQ * 64 + 255) / 256, 256, 0, stream>>>(tab);
  wprep_kernel<<<192, 256, 0, stream>>>(Wqkv, bqkv, Wb, bb);
  fused_qkv_attn<<<B, 512, 0, stream>>>(x, Wb, bb, tab, out);
  fc2_silu_kernel<<<(B * L_SEQ) / 128, 256, 0, stream>>>(Wfc2, bfc2, out);
}